// Round 1
// baseline (137.442 us; speedup 1.0000x reference)
//
#include <hip/hip_runtime.h>
#include <hip/hip_bf16.h>

typedef __attribute__((ext_vector_type(8))) short short8;
typedef __attribute__((ext_vector_type(4))) float f32x4;

#define LDSW 136  // padded row stride (bf16 elems) = 272 B: +16B pad rotates banks by 4/row

// round-to-nearest-even f32 -> bf16 (inputs are finite normals; NaN path not needed)
static __device__ __forceinline__ ushort f2bf(float f) {
  unsigned int u = __builtin_bit_cast(unsigned int, f);
  u += 0x7fffu + ((u >> 16) & 1u);
  return (ushort)(u >> 16);
}

// ---------------- kernel 1: pack w1 (f32 row-major) -> bf16 [col][k] with padded stride ----
__global__ __launch_bounds__(256) void pack_w1_kernel(const float* __restrict__ w1,
                                                      ushort* __restrict__ w1p) {
  int tid = blockIdx.x * 256 + threadIdx.x;  // 64 blocks * 256 = 16384 = 128*128
  int k = tid >> 7;
  int c = tid & 127;
  w1p[c * LDSW + k] = f2bf(w1[k * 128 + c]);  // coalesced read over c; tiny scattered write
}

// ---------------- kernel 2: column-sum partials (deterministic, no atomics) ----------------
__global__ __launch_bounds__(256) void colsum_kernel(const float4* __restrict__ x4,
                                                     float4* __restrict__ partial4, int n) {
  __shared__ float4 red[8][32];
  int tid = threadIdx.x;
  int c4 = tid & 31;   // which float4 column group (128 cols / 4)
  int rg = tid >> 5;   // row group 0..7
  float4 acc = {0.f, 0.f, 0.f, 0.f};
  for (int r = blockIdx.x * 8 + rg; r < n; r += 256 * 8) {
    float4 v = x4[r * 32 + c4];
    acc.x += v.x; acc.y += v.y; acc.z += v.z; acc.w += v.w;
  }
  red[rg][c4] = acc;
  __syncthreads();
  if (tid < 32) {
    float4 s = red[0][tid];
#pragma unroll
    for (int g = 1; g < 8; ++g) {
      float4 v = red[g][tid];
      s.x += v.x; s.y += v.y; s.z += v.z; s.w += v.w;
    }
    partial4[blockIdx.x * 32 + tid] = s;
  }
}

// ---------------- kernel 3: t = (pooled @ w2)/n + bias  (128 outputs) ----------------------
__global__ __launch_bounds__(128) void transmit_kernel(const float* __restrict__ partial,
                                                       const float* __restrict__ w2,
                                                       const float* __restrict__ bias,
                                                       float* __restrict__ t, int n,
                                                       int nblocks) {
  __shared__ float pooled[128];
  int j = threadIdx.x;
  float s = 0.f;
  for (int b = 0; b < nblocks; ++b) s += partial[b * 128 + j];  // coalesced over j
  pooled[j] = s;
  __syncthreads();
  float acc = 0.f;
#pragma unroll 8
  for (int i = 0; i < 128; ++i) acc += pooled[i] * w2[i * 128 + j];
  t[j] = acc / (float)n + bias[j];
}

// ---------------- kernel 4: out = x @ w1 + t  (bf16 MFMA, f32 accumulate) ------------------
__global__ __launch_bounds__(256) void gemm_kernel(const float* __restrict__ x,
                                                   const ushort* __restrict__ w1p,
                                                   const float* __restrict__ tvec,
                                                   float* __restrict__ out) {
  __shared__ ushort w1t[128 * LDSW];  // 34816 B, includes pad
  __shared__ float t_lds[128];
  int tid = threadIdx.x;

  // stage packed w1 (pad included) linearly: 2176 x 16B chunks, conflict-free
  {
    const ulonglong2* src = reinterpret_cast<const ulonglong2*>(w1p);
    ulonglong2* dst = reinterpret_cast<ulonglong2*>(w1t);
#pragma unroll
    for (int i = 0; i < (128 * LDSW * 2) / 16 / 256 + 1; ++i) {
      int idx = tid + i * 256;
      if (idx < (128 * LDSW * 2) / 16) dst[idx] = src[idx];
    }
  }
  if (tid < 128) t_lds[tid] = tvec[tid];
  __syncthreads();

  int lane = tid & 63;
  int wave = tid >> 6;
  int c = lane & 15;    // A: row-in-tile / B: col / D: col
  int kg = lane >> 4;   // k-group 0..3 (8 consecutive k each)
  int rbase = blockIdx.x * 64 + wave * 16;
  const float* xrow = x + (size_t)(rbase + c) * 128;

  f32x4 acc[8];
#pragma unroll
  for (int nb = 0; nb < 8; ++nb) acc[nb] = (f32x4){0.f, 0.f, 0.f, 0.f};

#pragma unroll
  for (int kb = 0; kb < 4; ++kb) {
    int k0 = kb * 32 + kg * 8;
    float4 a0 = *reinterpret_cast<const float4*>(xrow + k0);
    float4 a1 = *reinterpret_cast<const float4*>(xrow + k0 + 4);
    short8 afrag;
    afrag[0] = (short)f2bf(a0.x);
    afrag[1] = (short)f2bf(a0.y);
    afrag[2] = (short)f2bf(a0.z);
    afrag[3] = (short)f2bf(a0.w);
    afrag[4] = (short)f2bf(a1.x);
    afrag[5] = (short)f2bf(a1.y);
    afrag[6] = (short)f2bf(a1.z);
    afrag[7] = (short)f2bf(a1.w);
#pragma unroll
    for (int nb = 0; nb < 8; ++nb) {
      short8 bfrag = *reinterpret_cast<const short8*>(&w1t[(nb * 16 + c) * LDSW + k0]);
      acc[nb] = __builtin_amdgcn_mfma_f32_16x16x32_bf16(afrag, bfrag, acc[nb], 0, 0, 0);
    }
  }

  // D layout (m89-verified): col = lane&15, row = (lane>>4)*4 + reg
#pragma unroll
  for (int nb = 0; nb < 8; ++nb) {
    int col = nb * 16 + c;
    float tv = t_lds[col];
#pragma unroll
    for (int i = 0; i < 4; ++i) {
      out[(size_t)(rbase + kg * 4 + i) * 128 + col] = acc[nb][i] + tv;
    }
  }
}

extern "C" void kernel_launch(void* const* d_in, const int* in_sizes, int n_in,
                              void* d_out, int out_size, void* d_ws, size_t ws_size,
                              hipStream_t stream) {
  const float* x = (const float*)d_in[0];
  const float* w1 = (const float*)d_in[1];
  const float* w2 = (const float*)d_in[2];
  const float* bias = (const float*)d_in[3];
  float* out = (float*)d_out;
  int n = in_sizes[0] / 128;  // 200000

  char* ws = (char*)d_ws;
  float* t = (float*)ws;                         // 512 B
  ushort* w1p = (ushort*)(ws + 512);             // 128*136*2 = 34816 B
  float* partial = (float*)(ws + 512 + 34816);   // 256*128*4 = 131072 B (16B-aligned: 35328)

  hipLaunchKernelGGL(pack_w1_kernel, dim3(64), dim3(256), 0, stream, w1, w1p);
  hipLaunchKernelGGL(colsum_kernel, dim3(256), dim3(256), 0, stream,
                     (const float4*)x, (float4*)partial, n);
  hipLaunchKernelGGL(transmit_kernel, dim3(1), dim3(128), 0, stream,
                     partial, w2, bias, t, n, 256);
  hipLaunchKernelGGL(gemm_kernel, dim3(n / 64), dim3(256), 0, stream, x, w1p, t, out);
}

// Round 2
// 83.234 us; speedup vs baseline: 1.6513x; 1.6513x over previous
//
#include <hip/hip_runtime.h>
#include <hip/hip_bf16.h>

typedef __attribute__((ext_vector_type(8))) short short8;
typedef __attribute__((ext_vector_type(4))) float f32x4;

#define LDSW 136  // padded row stride (bf16 elems) = 272 B: +16B pad rotates banks by 4/row

// round-to-nearest-even f32 -> bf16 (inputs are finite normals; NaN path not needed)
static __device__ __forceinline__ ushort f2bf(float f) {
  unsigned int u = __builtin_bit_cast(unsigned int, f);
  u += 0x7fffu + ((u >> 16) & 1u);
  return (ushort)(u >> 16);
}

// ---------------- kernel 1: pack w1 (f32 row-major) -> bf16 [col][k] with padded stride ----
__global__ __launch_bounds__(256) void pack_w1_kernel(const float* __restrict__ w1,
                                                      ushort* __restrict__ w1p) {
  int tid = blockIdx.x * 256 + threadIdx.x;  // 64 blocks * 256 = 16384 = 128*128
  int k = tid >> 7;
  int c = tid & 127;
  w1p[c * LDSW + k] = f2bf(w1[k * 128 + c]);  // coalesced read over c; tiny scattered write
}

// ---------------- kernel 2: column-sum partials (deterministic, no atomics) ----------------
__global__ __launch_bounds__(256) void colsum_kernel(const float4* __restrict__ x4,
                                                     float4* __restrict__ partial4, int n) {
  __shared__ float4 red[8][32];
  int tid = threadIdx.x;
  int c4 = tid & 31;   // which float4 column group (128 cols / 4)
  int rg = tid >> 5;   // row group 0..7
  float4 acc = {0.f, 0.f, 0.f, 0.f};
  for (int r = blockIdx.x * 8 + rg; r < n; r += 256 * 8) {
    float4 v = x4[r * 32 + c4];
    acc.x += v.x; acc.y += v.y; acc.z += v.z; acc.w += v.w;
  }
  red[rg][c4] = acc;
  __syncthreads();
  if (tid < 32) {
    float4 s = red[0][tid];
#pragma unroll
    for (int g = 1; g < 8; ++g) {
      float4 v = red[g][tid];
      s.x += v.x; s.y += v.y; s.z += v.z; s.w += v.w;
    }
    partial4[blockIdx.x * 32 + tid] = s;
  }
}

// ---------------- kernel 3: t = (pooled @ w2)/n + bias  (parallel: 1024 thr, 16 waves) -----
__global__ __launch_bounds__(1024) void transmit_kernel(const float* __restrict__ partial,
                                                        const float* __restrict__ w2,
                                                        const float* __restrict__ bias,
                                                        float* __restrict__ t, int n,
                                                        int nblocks) {
  __shared__ float red[8][128];
  __shared__ float pooled[128];
  int tid = threadIdx.x;
  int j = tid & 127;   // column
  int g = tid >> 7;    // group 0..7

  // phase 1: reduce partial[256][128] -> pooled[128]; each group sums 32 rows (coalesced)
  float s = 0.f;
  for (int b = g; b < nblocks; b += 8) s += partial[b * 128 + j];
  red[g][j] = s;
  __syncthreads();
  if (tid < 128) {
    float p = 0.f;
#pragma unroll
    for (int gg = 0; gg < 8; ++gg) p += red[gg][j];
    pooled[j] = p;
  }
  __syncthreads();

  // phase 2: matvec pooled @ w2; group g handles i in [g*16, (g+1)*16)
  float acc = 0.f;
#pragma unroll
  for (int ii = 0; ii < 16; ++ii) {
    int i = g * 16 + ii;
    acc += pooled[i] * w2[i * 128 + j];  // coalesced over j
  }
  __syncthreads();  // pooled reads done before red reuse (same lds region distinct, but be safe)
  red[g][j] = acc;
  __syncthreads();
  if (tid < 128) {
    float a = 0.f;
#pragma unroll
    for (int gg = 0; gg < 8; ++gg) a += red[gg][j];
    t[j] = a / (float)n + bias[j];
  }
}

// ---------------- kernel 4: out = x @ w1 + t  (bf16 MFMA, f32 accumulate) ------------------
__global__ __launch_bounds__(256) void gemm_kernel(const float* __restrict__ x,
                                                   const ushort* __restrict__ w1p,
                                                   const float* __restrict__ tvec,
                                                   float* __restrict__ out) {
  __shared__ ushort w1t[128 * LDSW];  // 34816 B, includes pad
  __shared__ float t_lds[128];
  int tid = threadIdx.x;

  // stage packed w1 (pad included) linearly: 2176 x 16B chunks, conflict-free
  {
    const ulonglong2* src = reinterpret_cast<const ulonglong2*>(w1p);
    ulonglong2* dst = reinterpret_cast<ulonglong2*>(w1t);
#pragma unroll
    for (int i = 0; i < (128 * LDSW * 2) / 16 / 256 + 1; ++i) {
      int idx = tid + i * 256;
      if (idx < (128 * LDSW * 2) / 16) dst[idx] = src[idx];
    }
  }
  if (tid < 128) t_lds[tid] = tvec[tid];
  __syncthreads();

  int lane = tid & 63;
  int wave = tid >> 6;
  int c = lane & 15;    // A: row-in-tile / B: col / D: col
  int kg = lane >> 4;   // k-group 0..3 (8 consecutive k each)
  int rbase = blockIdx.x * 64 + wave * 16;
  const float* xrow = x + (size_t)(rbase + c) * 128;

  f32x4 acc[8];
#pragma unroll
  for (int nb = 0; nb < 8; ++nb) acc[nb] = (f32x4){0.f, 0.f, 0.f, 0.f};

#pragma unroll
  for (int kb = 0; kb < 4; ++kb) {
    int k0 = kb * 32 + kg * 8;
    float4 a0 = *reinterpret_cast<const float4*>(xrow + k0);
    float4 a1 = *reinterpret_cast<const float4*>(xrow + k0 + 4);
    short8 afrag;
    afrag[0] = (short)f2bf(a0.x);
    afrag[1] = (short)f2bf(a0.y);
    afrag[2] = (short)f2bf(a0.z);
    afrag[3] = (short)f2bf(a0.w);
    afrag[4] = (short)f2bf(a1.x);
    afrag[5] = (short)f2bf(a1.y);
    afrag[6] = (short)f2bf(a1.z);
    afrag[7] = (short)f2bf(a1.w);
#pragma unroll
    for (int nb = 0; nb < 8; ++nb) {
      short8 bfrag = *reinterpret_cast<const short8*>(&w1t[(nb * 16 + c) * LDSW + k0]);
      acc[nb] = __builtin_amdgcn_mfma_f32_16x16x32_bf16(afrag, bfrag, acc[nb], 0, 0, 0);
    }
  }

  // D layout (m89-verified): col = lane&15, row = (lane>>4)*4 + reg
#pragma unroll
  for (int nb = 0; nb < 8; ++nb) {
    int col = nb * 16 + c;
    float tv = t_lds[col];
#pragma unroll
    for (int i = 0; i < 4; ++i) {
      out[(size_t)(rbase + kg * 4 + i) * 128 + col] = acc[nb][i] + tv;
    }
  }
}

extern "C" void kernel_launch(void* const* d_in, const int* in_sizes, int n_in,
                              void* d_out, int out_size, void* d_ws, size_t ws_size,
                              hipStream_t stream) {
  const float* x = (const float*)d_in[0];
  const float* w1 = (const float*)d_in[1];
  const float* w2 = (const float*)d_in[2];
  const float* bias = (const float*)d_in[3];
  float* out = (float*)d_out;
  int n = in_sizes[0] / 128;  // 200000

  char* ws = (char*)d_ws;
  float* t = (float*)ws;                         // 512 B
  ushort* w1p = (ushort*)(ws + 512);             // 128*136*2 = 34816 B
  float* partial = (float*)(ws + 512 + 34816);   // 256*128*4 = 131072 B (16B-aligned: 35328)

  hipLaunchKernelGGL(pack_w1_kernel, dim3(64), dim3(256), 0, stream, w1, w1p);
  hipLaunchKernelGGL(colsum_kernel, dim3(256), dim3(256), 0, stream,
                     (const float4*)x, (float4*)partial, n);
  hipLaunchKernelGGL(transmit_kernel, dim3(1), dim3(1024), 0, stream,
                     partial, w2, bias, t, n, 256);
  hipLaunchKernelGGL(gemm_kernel, dim3(n / 64), dim3(256), 0, stream, x, w1p, t, out);
}

// Round 3
// 80.696 us; speedup vs baseline: 1.7032x; 1.0315x over previous
//
#include <hip/hip_runtime.h>
#include <hip/hip_bf16.h>

typedef __attribute__((ext_vector_type(8))) short short8;
typedef __attribute__((ext_vector_type(4))) float f32x4;

#define LDSW 136       // padded row stride (bf16 elems) = 272 B: +16B pad rotates banks by 4/row
#define CS_BLOCKS 512  // colsum grid: 512 blocks x 1024 thr = 32 waves/CU (max occupancy)

// round-to-nearest-even f32 -> bf16 (inputs are finite normals; NaN path not needed)
static __device__ __forceinline__ ushort f2bf(float f) {
  unsigned int u = __builtin_bit_cast(unsigned int, f);
  u += 0x7fffu + ((u >> 16) & 1u);
  return (ushort)(u >> 16);
}

// ---------------- kernel 1: pack w1 (f32 row-major) -> bf16 [col][k] with padded stride ----
__global__ __launch_bounds__(256) void pack_w1_kernel(const float* __restrict__ w1,
                                                      ushort* __restrict__ w1p) {
  int tid = blockIdx.x * 256 + threadIdx.x;  // 64 blocks * 256 = 16384 = 128*128
  int k = tid >> 7;
  int c = tid & 127;
  w1p[c * LDSW + k] = f2bf(w1[k * 128 + c]);  // coalesced read over c; tiny scattered write
}

// ---------------- kernel 2: column-sum partials (deterministic, no atomics) ----------------
// 512 blocks x 1024 threads: each block covers 32 rows per grid-step, tree-reduces in LDS.
__global__ __launch_bounds__(1024) void colsum_kernel(const float4* __restrict__ x4,
                                                      float4* __restrict__ partial4, int n) {
  __shared__ float4 red[32][32];  // 16 KB
  int tid = threadIdx.x;
  int c4 = tid & 31;   // float4 column group (128 cols / 4)
  int rg = tid >> 5;   // row group 0..31
  float4 acc = {0.f, 0.f, 0.f, 0.f};
#pragma unroll 4
  for (int r = blockIdx.x * 32 + rg; r < n; r += CS_BLOCKS * 32) {
    float4 v = x4[(size_t)r * 32 + c4];
    acc.x += v.x; acc.y += v.y; acc.z += v.z; acc.w += v.w;
  }
  red[rg][c4] = acc;
  __syncthreads();
#pragma unroll
  for (int s = 16; s >= 1; s >>= 1) {
    if (rg < s) {
      float4 a = red[rg][c4];
      float4 b = red[rg + s][c4];
      a.x += b.x; a.y += b.y; a.z += b.z; a.w += b.w;
      red[rg][c4] = a;
    }
    __syncthreads();
  }
  if (tid < 32) partial4[blockIdx.x * 32 + tid] = red[0][tid];
}

// ---------------- kernel 3: t = (pooled @ w2)/n + bias  (parallel: 1024 thr, 16 waves) -----
__global__ __launch_bounds__(1024) void transmit_kernel(const float* __restrict__ partial,
                                                        const float* __restrict__ w2,
                                                        const float* __restrict__ bias,
                                                        float* __restrict__ t, int n,
                                                        int nblocks) {
  __shared__ float red[8][128];
  __shared__ float pooled[128];
  int tid = threadIdx.x;
  int j = tid & 127;   // column
  int g = tid >> 7;    // group 0..7

  // phase 1: reduce partial[nblocks][128] -> pooled[128]; coalesced over j
  float s = 0.f;
  for (int b = g; b < nblocks; b += 8) s += partial[b * 128 + j];
  red[g][j] = s;
  __syncthreads();
  if (tid < 128) {
    float p = 0.f;
#pragma unroll
    for (int gg = 0; gg < 8; ++gg) p += red[gg][j];
    pooled[j] = p;
  }
  __syncthreads();

  // phase 2: matvec pooled @ w2; group g handles i in [g*16, (g+1)*16)
  float acc = 0.f;
#pragma unroll
  for (int ii = 0; ii < 16; ++ii) {
    int i = g * 16 + ii;
    acc += pooled[i] * w2[i * 128 + j];  // coalesced over j
  }
  __syncthreads();
  red[g][j] = acc;
  __syncthreads();
  if (tid < 128) {
    float a = 0.f;
#pragma unroll
    for (int gg = 0; gg < 8; ++gg) a += red[gg][j];
    t[j] = a / (float)n + bias[j];
  }
}

// ---------------- kernel 4: out = x @ w1 + t  (bf16 MFMA, f32 accumulate) ------------------
__global__ __launch_bounds__(256) void gemm_kernel(const float* __restrict__ x,
                                                   const ushort* __restrict__ w1p,
                                                   const float* __restrict__ tvec,
                                                   float* __restrict__ out) {
  __shared__ ushort w1t[128 * LDSW];  // 34816 B, includes pad
  __shared__ float t_lds[128];
  int tid = threadIdx.x;

  // stage packed w1 (pad included) linearly: 2176 x 16B chunks, conflict-free
  {
    const ulonglong2* src = reinterpret_cast<const ulonglong2*>(w1p);
    ulonglong2* dst = reinterpret_cast<ulonglong2*>(w1t);
#pragma unroll
    for (int i = 0; i < (128 * LDSW * 2) / 16 / 256 + 1; ++i) {
      int idx = tid + i * 256;
      if (idx < (128 * LDSW * 2) / 16) dst[idx] = src[idx];
    }
  }
  if (tid < 128) t_lds[tid] = tvec[tid];
  __syncthreads();

  int lane = tid & 63;
  int wave = tid >> 6;
  int c = lane & 15;    // A: row-in-tile / B: col / D: col
  int kg = lane >> 4;   // k-group 0..3 (8 consecutive k each)
  int rbase = blockIdx.x * 64 + wave * 16;
  const float* xrow = x + (size_t)(rbase + c) * 128;

  f32x4 acc[8];
#pragma unroll
  for (int nb = 0; nb < 8; ++nb) acc[nb] = (f32x4){0.f, 0.f, 0.f, 0.f};

#pragma unroll
  for (int kb = 0; kb < 4; ++kb) {
    int k0 = kb * 32 + kg * 8;
    float4 a0 = *reinterpret_cast<const float4*>(xrow + k0);
    float4 a1 = *reinterpret_cast<const float4*>(xrow + k0 + 4);
    short8 afrag;
    afrag[0] = (short)f2bf(a0.x);
    afrag[1] = (short)f2bf(a0.y);
    afrag[2] = (short)f2bf(a0.z);
    afrag[3] = (short)f2bf(a0.w);
    afrag[4] = (short)f2bf(a1.x);
    afrag[5] = (short)f2bf(a1.y);
    afrag[6] = (short)f2bf(a1.z);
    afrag[7] = (short)f2bf(a1.w);
#pragma unroll
    for (int nb = 0; nb < 8; ++nb) {
      short8 bfrag = *reinterpret_cast<const short8*>(&w1t[(nb * 16 + c) * LDSW + k0]);
      acc[nb] = __builtin_amdgcn_mfma_f32_16x16x32_bf16(afrag, bfrag, acc[nb], 0, 0, 0);
    }
  }

  // D layout (m89-verified): col = lane&15, row = (lane>>4)*4 + reg
#pragma unroll
  for (int nb = 0; nb < 8; ++nb) {
    int col = nb * 16 + c;
    float tv = t_lds[col];
#pragma unroll
    for (int i = 0; i < 4; ++i) {
      out[(size_t)(rbase + kg * 4 + i) * 128 + col] = acc[nb][i] + tv;
    }
  }
}

extern "C" void kernel_launch(void* const* d_in, const int* in_sizes, int n_in,
                              void* d_out, int out_size, void* d_ws, size_t ws_size,
                              hipStream_t stream) {
  const float* x = (const float*)d_in[0];
  const float* w1 = (const float*)d_in[1];
  const float* w2 = (const float*)d_in[2];
  const float* bias = (const float*)d_in[3];
  float* out = (float*)d_out;
  int n = in_sizes[0] / 128;  // 200000

  char* ws = (char*)d_ws;
  float* t = (float*)ws;                         // 512 B
  ushort* w1p = (ushort*)(ws + 512);             // 128*136*2 = 34816 B
  float* partial = (float*)(ws + 512 + 34816);   // CS_BLOCKS*128*4 = 262144 B

  hipLaunchKernelGGL(pack_w1_kernel, dim3(64), dim3(256), 0, stream, w1, w1p);
  hipLaunchKernelGGL(colsum_kernel, dim3(CS_BLOCKS), dim3(1024), 0, stream,
                     (const float4*)x, (float4*)partial, n);
  hipLaunchKernelGGL(transmit_kernel, dim3(1), dim3(1024), 0, stream,
                     partial, w2, bias, t, n, CS_BLOCKS);
  hipLaunchKernelGGL(gemm_kernel, dim3(n / 64), dim3(256), 0, stream, x, w1p, t, out);
}